// Round 5
// baseline (456.199 us; speedup 1.0000x reference)
//
#include <hip/hip_runtime.h>
#include <cmath>

// Problem constants
#define B_SZ   32
#define LQ     576
#define LV     3024
#define CDIM   384
#define NHEAD  6
#define DHEAD  64
#define NLVL   3
#define NPTS   4
#define NPROJ  216   // 144 offset channels + 72 attn logits

typedef short  bx4 __attribute__((ext_vector_type(4)));
typedef short  bx8 __attribute__((ext_vector_type(8)));
typedef float  fx4 __attribute__((ext_vector_type(4)));

__device__ __forceinline__ short f2bf(float f) {
    unsigned u = __builtin_bit_cast(unsigned, f);
    unsigned r = (u + 0x7FFFu + ((u >> 16) & 1u)) >> 16;  // RNE
    return (short)r;
}
__device__ __forceinline__ float bf2f(unsigned short u) {
    return __builtin_bit_cast(float, ((unsigned)u) << 16);
}

// ---------------------------------------------------------------------------
// W (K x N fp32) -> Wt (N x K bf16)   [384x384]
// ---------------------------------------------------------------------------
__global__ __launch_bounds__(256) void cast_transpose_kernel(
    const float* __restrict__ W, short* __restrict__ Wt, int K, int N)
{
    int idx = blockIdx.x * 256 + threadIdx.x;
    if (idx >= K * N) return;
    int n = idx / K, k = idx - n * K;
    Wt[idx] = f2bf(W[(size_t)k * N + n]);
}

// ---------------------------------------------------------------------------
// Split-bf16 concat weight for off+attn projection (fp32-grade path).
// ---------------------------------------------------------------------------
__global__ __launch_bounds__(256) void prep_proj_kernel(
    const float* __restrict__ W_off, const float* __restrict__ b_off,
    const float* __restrict__ W_attn, const float* __restrict__ b_attn,
    short* __restrict__ Wh, short* __restrict__ Wl, float* __restrict__ bc)
{
    int idx = blockIdx.x * 256 + threadIdx.x;
    if (idx >= NPROJ * CDIM) return;
    int n = idx / CDIM, k = idx - n * CDIM;
    float w = (n < 144) ? W_off[(size_t)k * 144 + n]
                        : W_attn[(size_t)k * 72 + (n - 144)];
    short h = f2bf(w);
    float hf = bf2f((unsigned short)h);
    Wh[idx] = h;
    Wl[idx] = f2bf(w - hf);
    if (idx < NPROJ) bc[idx] = (idx < 144) ? b_off[idx] : b_attn[idx - 144];
}

// ---------------------------------------------------------------------------
// Register-B bf16 MFMA GEMM: C[M,384] = A[M,K] @ Wt[384,K]^T + bias.
// Tile 128 rows x 192 cols (N-half); grid = (M/128)*2, pairs share the A
// tile via L2/L3. 256 threads = 4 waves, wave tile 64x96 (acc 4x6 fx4).
// B fragments are loaded DIRECTLY from global (Wt = 294 KB, L2-resident) --
// only the A tile goes through LDS (18.4 KB), cutting LDS bandwidth ~3x
// vs staging both operands (round-4 bottleneck: MfmaUtil capped at 11% by
// ds_read throughput). B loads issue before the A barrier -> in flight
// during the stall. launch_bounds(256,2): 2 waves/SIMD -> 2 blocks/CU.
// ---------------------------------------------------------------------------
template <bool A_FP32, bool OUT_BF16>
__global__ __launch_bounds__(256, 2) void gemm_regB_kernel(
    const void* __restrict__ Av, const short* __restrict__ Wt,
    const float* __restrict__ bias, void* __restrict__ Cout,
    int M, int K)
{
    constexpr int N = 384;
    __shared__ short As[128 * 72];

    const int tid = threadIdx.x;
    const int m0 = (blockIdx.x >> 1) * 128;
    const int n0 = (blockIdx.x & 1) * 192;

    const int w  = tid >> 6;           // wave 0..3
    const int l  = tid & 63;
    const int wr = (w & 1) * 64;       // row offset
    const int wc = (w >> 1) * 96;      // col offset (6 x 16)
    const int lr = l & 15;
    const int ko = (l >> 4) * 8;

    // Per-lane base pointer for direct B-fragment loads: Wt[n][k], n=col.
    const short* Bp = Wt + (size_t)(n0 + wc + lr) * K + ko;

    fx4 acc[4][6] = {};

    for (int k0 = 0; k0 < K; k0 += 64) {
        // ---- B fragments straight from global (L2-hot), in flight early ----
        bx8 bfr[2][6];
        #pragma unroll
        for (int ks = 0; ks < 2; ++ks)
            #pragma unroll
            for (int j = 0; j < 6; ++j)
                bfr[ks][j] = *(const bx8*)(Bp + (size_t)j * 16 * K + k0 + ks * 32);

        // ---- stage A tile into LDS ----
        if (A_FP32) {
            const float* A = (const float*)Av;
            #pragma unroll
            for (int r = 0; r < 8; ++r) {          // 128 rows x 16 float4
                const int id = tid + r * 256;
                const int m  = id >> 4;
                const int kq = (id & 15) << 2;
                const float4 v = *(const float4*)(A + (size_t)(m0 + m) * K + k0 + kq);
                bx4 s;
                s[0] = f2bf(v.x); s[1] = f2bf(v.y); s[2] = f2bf(v.z); s[3] = f2bf(v.w);
                *(bx4*)&As[m * 72 + kq] = s;
            }
        } else {
            const short* A = (const short*)Av;
            #pragma unroll
            for (int r = 0; r < 4; ++r) {          // 128 rows x 8 short8
                const int id = tid + r * 256;
                const int m  = id >> 3;
                const int k8 = (id & 7) << 3;
                *(bx8*)&As[m * 72 + k8] = *(const bx8*)(A + (size_t)(m0 + m) * K + k0 + k8);
            }
        }
        __syncthreads();

        #pragma unroll
        for (int ks = 0; ks < 2; ++ks) {
            bx8 af[4];
            #pragma unroll
            for (int i = 0; i < 4; ++i)
                af[i] = *(const bx8*)&As[(wr + i * 16 + lr) * 72 + ks * 32 + ko];
            #pragma unroll
            for (int i = 0; i < 4; ++i)
                #pragma unroll
                for (int j = 0; j < 6; ++j)
                    acc[i][j] = __builtin_amdgcn_mfma_f32_16x16x32_bf16(
                        af[i], bfr[ks][j], acc[i][j], 0, 0, 0);
        }
        __syncthreads();
    }

    // Epilogue: C/D layout col=lane&15, row=(lane>>4)*4+reg
    const int rrow = (l >> 4) * 4;
    #pragma unroll
    for (int j = 0; j < 6; ++j) {
        const int col = n0 + wc + j * 16 + lr;
        const float bv = bias[col];
        #pragma unroll
        for (int i = 0; i < 4; ++i) {
            const int row = m0 + wr + i * 16 + rrow;
            #pragma unroll
            for (int r = 0; r < 4; ++r) {
                if (OUT_BF16)
                    ((short*)Cout)[(size_t)(row + r) * N + col] = f2bf(acc[i][j][r] + bv);
                else
                    ((float*)Cout)[(size_t)(row + r) * N + col] = acc[i][j][r] + bv;
            }
        }
    }
}

// ---------------------------------------------------------------------------
// Split-bf16 MFMA GEMM for query projections (fp32-grade):
//   acc += Ah*Bh + Ah*Bl + Al*Bh.  128x128 tile, BK=32, 256 threads.
// ---------------------------------------------------------------------------
__global__ __launch_bounds__(256) void gemm_proj_split_kernel(
    const float* __restrict__ A, const short* __restrict__ Wh,
    const short* __restrict__ Wl, const float* __restrict__ bias,
    float* __restrict__ C, int M, int N, int K)
{
    __shared__ short Ah[128 * 40];
    __shared__ short Al[128 * 40];
    __shared__ short Bh[128 * 40];
    __shared__ short Bl[128 * 40];

    const int tid = threadIdx.x;
    const int m0 = blockIdx.y * 128;
    const int n0 = blockIdx.x * 128;

    const int kq = (tid & 7) << 2;
    const int rw = tid >> 3;

    const int w  = tid >> 6;
    const int l  = tid & 63;
    const int mw = (w & 1) * 64;
    const int nw = (w >> 1) * 64;
    const int lr = l & 15;
    const int ko = (l >> 4) * 8;

    fx4 acc[4][4] = {};

    for (int k0 = 0; k0 < K; k0 += 32) {
        #pragma unroll
        for (int r = 0; r < 4; ++r) {
            const int m = rw + r * 32;
            const float4 v = *(const float4*)(A + (size_t)(m0 + m) * K + k0 + kq);
            bx4 sh, sl;
            #pragma unroll
            for (int t = 0; t < 4; ++t) {
                const float f = ((const float*)&v)[t];
                const short h = f2bf(f);
                sh[t] = h;
                sl[t] = f2bf(f - bf2f((unsigned short)h));
            }
            *(bx4*)&Ah[m * 40 + kq] = sh;
            *(bx4*)&Al[m * 40 + kq] = sl;

            bx4 wh = {}, wl = {};
            if (n0 + m < N) {
                wh = *(const bx4*)(Wh + (size_t)(n0 + m) * K + k0 + kq);
                wl = *(const bx4*)(Wl + (size_t)(n0 + m) * K + k0 + kq);
            }
            *(bx4*)&Bh[m * 40 + kq] = wh;
            *(bx4*)&Bl[m * 40 + kq] = wl;
        }
        __syncthreads();

        bx8 ah[4], al[4], bh[4], bl[4];
        #pragma unroll
        for (int i = 0; i < 4; ++i) {
            ah[i] = *(const bx8*)&Ah[(mw + i * 16 + lr) * 40 + ko];
            al[i] = *(const bx8*)&Al[(mw + i * 16 + lr) * 40 + ko];
        }
        #pragma unroll
        for (int j = 0; j < 4; ++j) {
            bh[j] = *(const bx8*)&Bh[(nw + j * 16 + lr) * 40 + ko];
            bl[j] = *(const bx8*)&Bl[(nw + j * 16 + lr) * 40 + ko];
        }
        #pragma unroll
        for (int i = 0; i < 4; ++i)
            #pragma unroll
            for (int j = 0; j < 4; ++j) {
                acc[i][j] = __builtin_amdgcn_mfma_f32_16x16x32_bf16(al[i], bh[j], acc[i][j], 0, 0, 0);
                acc[i][j] = __builtin_amdgcn_mfma_f32_16x16x32_bf16(ah[i], bl[j], acc[i][j], 0, 0, 0);
                acc[i][j] = __builtin_amdgcn_mfma_f32_16x16x32_bf16(ah[i], bh[j], acc[i][j], 0, 0, 0);
            }
        __syncthreads();
    }

    const int rrow = (l >> 4) * 4;
    #pragma unroll
    for (int j = 0; j < 4; ++j) {
        const int col = n0 + nw + j * 16 + lr;
        if (col >= N) continue;
        const float bv = bias[col];
        #pragma unroll
        for (int i = 0; i < 4; ++i) {
            const int row = m0 + mw + i * 16 + rrow;
            #pragma unroll
            for (int r = 0; r < 4; ++r)
                C[(size_t)(row + r) * N + col] = acc[i][j][r] + bv;
        }
    }
}

// ---------------------------------------------------------------------------
// Reference-point processing (verified round 1)
// ---------------------------------------------------------------------------
__global__ __launch_bounds__(256) void ref_kernel(
    const float* __restrict__ rp, float* __restrict__ refp)
{
    const int b = blockIdx.x;
    const float* r = rp + (size_t)b * LV * 2;
    const int tid = threadIdx.x;

    __shared__ float redx[256], redy[256];
    float sx = 0.f, sy = 0.f;
    for (int i = tid; i < 2304; i += 256) {
        sx += r[2 * i + 0];
        sy += r[2 * i + 1];
    }
    redx[tid] = sx; redy[tid] = sy;
    __syncthreads();
    for (int s = 128; s > 0; s >>= 1) {
        if (tid < s) { redx[tid] += redx[tid + s]; redy[tid] += redy[tid + s]; }
        __syncthreads();
    }
    const float p1x = redx[0] * (1.f / 2304.f);
    const float p1y = redy[0] * (1.f / 2304.f);

    const float* g = r + 2880 * 2;
    for (int q = tid; q < 576; q += 256) {
        const float p2x = r[(2304 + q) * 2 + 0];
        const float p2y = r[(2304 + q) * 2 + 1];
        const int qy = q / 24, qx = q % 24;
        const float syc = fminf(fmaxf(0.5f * qy - 0.25f, 0.f), 11.f);
        const float sxc = fminf(fmaxf(0.5f * qx - 0.25f, 0.f), 11.f);
        int y0 = min((int)syc, 10);
        int x0 = min((int)sxc, 10);
        const float fy = syc - (float)y0, fx = sxc - (float)x0;
        const float v00x = g[(y0 * 12 + x0) * 2 + 0],     v00y = g[(y0 * 12 + x0) * 2 + 1];
        const float v10x = g[(y0 * 12 + x0 + 1) * 2 + 0], v10y = g[(y0 * 12 + x0 + 1) * 2 + 1];
        const float v01x = g[((y0 + 1) * 12 + x0) * 2 + 0],     v01y = g[((y0 + 1) * 12 + x0) * 2 + 1];
        const float v11x = g[((y0 + 1) * 12 + x0 + 1) * 2 + 0], v11y = g[((y0 + 1) * 12 + x0 + 1) * 2 + 1];
        const float p3x = (1.f - fy) * ((1.f - fx) * v00x + fx * v10x)
                        + fy * ((1.f - fx) * v01x + fx * v11x);
        const float p3y = (1.f - fy) * ((1.f - fx) * v00y + fx * v10y)
                        + fy * ((1.f - fx) * v01y + fx * v11y);
        refp[((size_t)b * LQ + q) * 2 + 0] = (p1x + p2x + p3x) * (1.f / 3.f);
        refp[((size_t)b * LQ + q) * 2 + 1] = (p1y + p2y + p3y) * (1.f / 3.f);
    }
}

// ---------------------------------------------------------------------------
// Deformable sampling + softmax + attention accumulate (verified round 3).
// ---------------------------------------------------------------------------
__global__ __launch_bounds__(384) void sample_kernel(
    const unsigned short* __restrict__ val, const float* __restrict__ proj,
    const float* __restrict__ refp, short* __restrict__ mid)
{
    const int i = blockIdx.x;
    const int g = i & 7;           // XCD group swizzle
    const int r = i >> 3;
    const int b = g * 4 + (r / LQ);
    const int q = r - (r / LQ) * LQ;
    const int bq = b * LQ + q;
    const int tid = threadIdx.x;

    __shared__ float attn[72];
    __shared__ int   sloc[72][4];
    __shared__ float swt[72][4];

    if (tid < 72) {
        attn[tid] = proj[(size_t)bq * NPROJ + 144 + tid];

        const int h = tid / 12;
        const int rr = tid % 12;
        const int l = rr >> 2;
        const int p = rr & 3;

        const int HL[3] = {48, 24, 12};
        const int ST[3] = {0, 2304, 2880};
        const int Hl = HL[l], Wl = HL[l], st = ST[l];

        const float rx = refp[bq * 2 + 0];
        const float ry = refp[bq * 2 + 1];
        const int oc = ((h * NLVL + l) * NPTS + p) * 2;
        const float cx = proj[(size_t)bq * NPROJ + oc + 0] + rx;
        const float cy = proj[(size_t)bq * NPROJ + oc + 1] + ry;

        const float px = cx * (float)Wl - 0.5f;
        const float py = cy * (float)Hl - 0.5f;
        const float x0f = floorf(px), y0f = floorf(py);
        const float lx = px - x0f, ly = py - y0f;
        const int x0 = (int)x0f, y0 = (int)y0f;

        #pragma unroll
        for (int k = 0; k < 4; ++k) {
            const int dx = k & 1, dy = k >> 1;
            const int xi = x0 + dx, yi = y0 + dy;
            const bool v = (xi >= 0) && (xi < Wl) && (yi >= 0) && (yi < Hl);
            const int xc = min(max(xi, 0), Wl - 1);
            const int yc = min(max(yi, 0), Hl - 1);
            sloc[tid][k] = st + yc * Wl + xc;
            const float wx = dx ? lx : 1.f - lx;
            const float wy = dy ? ly : 1.f - ly;
            swt[tid][k] = v ? wx * wy : 0.f;
        }
    }
    __syncthreads();

    if (tid < NHEAD) {
        float mx = -1e30f;
        #pragma unroll
        for (int j = 0; j < 12; ++j) mx = fmaxf(mx, attn[tid * 12 + j]);
        float s = 0.f;
        #pragma unroll
        for (int j = 0; j < 12; ++j) {
            const float e = expf(attn[tid * 12 + j] - mx);
            attn[tid * 12 + j] = e;
            s += e;
        }
        const float inv = 1.f / s;
        #pragma unroll
        for (int j = 0; j < 12; ++j) attn[tid * 12 + j] *= inv;
    }
    __syncthreads();

    const int h = tid >> 6;
    const int c = tid & 63;
    const unsigned short* vb = val + (size_t)b * LV * CDIM + h * DHEAD + c;
    float acc = 0.f;
    #pragma unroll
    for (int s = 0; s < 12; ++s) {
        const int j = h * 12 + s;
        const float a = attn[j];
        const float sum = swt[j][0] * bf2f(vb[(size_t)sloc[j][0] * CDIM])
                        + swt[j][1] * bf2f(vb[(size_t)sloc[j][1] * CDIM])
                        + swt[j][2] * bf2f(vb[(size_t)sloc[j][2] * CDIM])
                        + swt[j][3] * bf2f(vb[(size_t)sloc[j][3] * CDIM]);
        acc += a * sum;
    }
    mid[(size_t)bq * CDIM + tid] = f2bf(acc);
}

// ---------------------------------------------------------------------------
extern "C" void kernel_launch(void* const* d_in, const int* in_sizes, int n_in,
                              void* d_out, int out_size, void* d_ws, size_t ws_size,
                              hipStream_t stream)
{
    (void)in_sizes; (void)n_in; (void)out_size; (void)ws_size;

    const float* query   = (const float*)d_in[0];
    const float* value   = (const float*)d_in[1];
    const float* rp      = (const float*)d_in[2];
    const float* W_value = (const float*)d_in[3];
    const float* b_value = (const float*)d_in[4];
    const float* W_off   = (const float*)d_in[5];
    const float* b_off   = (const float*)d_in[6];
    const float* W_attn  = (const float*)d_in[7];
    const float* b_attn  = (const float*)d_in[8];
    const float* W_out   = (const float*)d_in[9];
    const float* b_out   = (const float*)d_in[10];
    float* out = (float*)d_out;

    // Workspace layout (256-B aligned chunks)
    char* p = (char*)d_ws;
    auto take = [&](size_t bytes) { char* q = p; p += (bytes + 255) & ~(size_t)255; return q; };
    short* val  = (short*)take((size_t)B_SZ * LV * CDIM * 2);     // bf16 val
    short* mid  = (short*)take((size_t)B_SZ * LQ * CDIM * 2);     // bf16 mid
    short* Wtv  = (short*)take((size_t)CDIM * CDIM * 2);          // bf16 W_value^T
    short* Wto  = (short*)take((size_t)CDIM * CDIM * 2);          // bf16 W_out^T
    short* Wh   = (short*)take((size_t)NPROJ * CDIM * 2);
    short* Wl   = (short*)take((size_t)NPROJ * CDIM * 2);
    float* proj = (float*)take((size_t)B_SZ * LQ * NPROJ * 4);
    float* refp = (float*)take((size_t)B_SZ * LQ * 2 * 4);
    float* bc   = (float*)take((size_t)NPROJ * 4);

    const int Mv = B_SZ * LV;   // 96768
    const int Mq = B_SZ * LQ;   // 18432

    // 0) weight prep (tiny)
    cast_transpose_kernel<<<(CDIM * CDIM + 255) / 256, 256, 0, stream>>>(
        W_value, Wtv, CDIM, CDIM);
    cast_transpose_kernel<<<(CDIM * CDIM + 255) / 256, 256, 0, stream>>>(
        W_out, Wto, CDIM, CDIM);
    prep_proj_kernel<<<(NPROJ * CDIM + 255) / 256, 256, 0, stream>>>(
        W_off, b_off, W_attn, b_attn, Wh, Wl, bc);

    // 1) val = bf16(value @ W_value + b_value)   (register-B MFMA)
    gemm_regB_kernel<true, true><<<(Mv / 128) * 2, 256, 0, stream>>>(
        value, Wtv, b_value, val, Mv, CDIM);
    // 2) proj = query @ [W_off|W_attn] + bias    (split-bf16, fp32-grade)
    gemm_proj_split_kernel<<<dim3((NPROJ + 127) / 128, Mq / 128), 256, 0, stream>>>(
        query, Wh, Wl, bc, proj, Mq, NPROJ, CDIM);
    // 3) reference points
    ref_kernel<<<B_SZ, 256, 0, stream>>>(rp, refp);
    // 4) softmax + deformable sampling (XCD-swizzled)
    sample_kernel<<<Mq, 384, 0, stream>>>(
        (const unsigned short*)val, proj, refp, mid);
    // 5) out = mid @ W_out + b_out               (register-B MFMA, bf16 A)
    gemm_regB_kernel<false, false><<<(Mq / 128) * 2, 256, 0, stream>>>(
        mid, Wto, b_out, out, Mq, CDIM);
}

// Round 6
// 426.752 us; speedup vs baseline: 1.0690x; 1.0690x over previous
//
#include <hip/hip_runtime.h>
#include <cmath>

// Problem constants
#define B_SZ   32
#define LQ     576
#define LV     3024
#define CDIM   384
#define NHEAD  6
#define DHEAD  64
#define NLVL   3
#define NPTS   4
#define NPROJ  216   // 144 offset channels + 72 attn logits
#define NPROJP 256   // padded to 2 x 128 col tiles

typedef short    bx4 __attribute__((ext_vector_type(4)));
typedef short    bx8 __attribute__((ext_vector_type(8)));
typedef float    fx4 __attribute__((ext_vector_type(4)));
typedef _Float16 hx8 __attribute__((ext_vector_type(8)));

__device__ __forceinline__ short f2bf(float f) {
    unsigned u = __builtin_bit_cast(unsigned, f);
    unsigned r = (u + 0x7FFFu + ((u >> 16) & 1u)) >> 16;  // RNE
    return (short)r;
}
__device__ __forceinline__ float bf2f(unsigned short u) {
    return __builtin_bit_cast(float, ((unsigned)u) << 16);
}
__device__ __forceinline__ short f2h(float f) {
    return __builtin_bit_cast(short, (_Float16)f);       // RNE
}

// ---------------------------------------------------------------------------
// W (K x N fp32) -> Wt (N x K bf16)   [384x384]
// ---------------------------------------------------------------------------
__global__ __launch_bounds__(256) void cast_transpose_kernel(
    const float* __restrict__ W, short* __restrict__ Wt, int K, int N)
{
    int idx = blockIdx.x * 256 + threadIdx.x;
    if (idx >= K * N) return;
    int n = idx / K, k = idx - n * K;
    Wt[idx] = f2bf(W[(size_t)k * N + n]);
}

// ---------------------------------------------------------------------------
// Concat f16 transposed weight for off+attn projection, zero-padded to
// NPROJP rows. Also builds padded bias.
// ---------------------------------------------------------------------------
__global__ __launch_bounds__(256) void prep_proj_f16_kernel(
    const float* __restrict__ W_off, const float* __restrict__ b_off,
    const float* __restrict__ W_attn, const float* __restrict__ b_attn,
    short* __restrict__ Wf, float* __restrict__ bc)
{
    int idx = blockIdx.x * 256 + threadIdx.x;
    if (idx >= NPROJP * CDIM) return;
    int n = idx / CDIM, k = idx - n * CDIM;
    float w = 0.f;
    if (n < 144)           w = W_off[(size_t)k * 144 + n];
    else if (n < NPROJ)    w = W_attn[(size_t)k * 72 + (n - 144)];
    Wf[idx] = f2h(w);
    if (idx < NPROJP)
        bc[idx] = (idx < 144) ? b_off[idx]
                 : (idx < NPROJ ? b_attn[idx - 144] : 0.f);
}

// ---------------------------------------------------------------------------
// Unified 128x128 MFMA GEMM: C[M, ldc] = A[M,K] @ Bt[N,K]^T + bias.
// 256 threads / 4 waves, wave tile 64x64, acc[4][4] = 64 AGPR -> with
// launch_bounds(256,3) gives 3 blocks/CU (12 waves/CU) for latency overlap
// (rounds 3-5 all capped at ~1.5-2 blocks/CU -> MfmaUtil 10%).
// LDS 2 x 128x72 shorts = 36.9 KB.
// ATYPE: 0 = fp32 A cast to bf16, 1 = bf16 A passthrough, 2 = fp32 A to f16.
// F16: use f16 MFMA (Bt holds f16 bits). NGUARD: guard C cols at Nact.
// Grid: (N/128, M/128); x = col tile varies fastest -> adjacent blocks share
// the A tile via L2/L3.
// ---------------------------------------------------------------------------
template <int ATYPE, bool F16, bool OUT_BF16, bool NGUARD>
__global__ __launch_bounds__(256, 3) void gemm128_kernel(
    const void* __restrict__ Av, const short* __restrict__ Bt,
    const float* __restrict__ bias, void* __restrict__ Cout,
    int M, int K, int Nact, int ldc)
{
    __shared__ short As[128 * 72];
    __shared__ short Bs[128 * 72];

    const int tid = threadIdx.x;
    const int n0 = blockIdx.x * 128;
    const int m0 = blockIdx.y * 128;

    const int w  = tid >> 6;
    const int l  = tid & 63;
    const int wr = (w & 1) * 64;
    const int wc = (w >> 1) * 64;
    const int lr = l & 15;
    const int ko = (l >> 4) * 8;

    fx4 acc[4][4] = {};

    for (int k0 = 0; k0 < K; k0 += 64) {
        if (ATYPE == 1) {
            const short* A = (const short*)Av;
            #pragma unroll
            for (int r = 0; r < 4; ++r) {              // 128 rows x 8 short8
                const int id = tid + r * 256;
                const int m  = id >> 3;
                const int k8 = (id & 7) << 3;
                *(bx8*)&As[m * 72 + k8] = *(const bx8*)(A + (size_t)(m0 + m) * K + k0 + k8);
            }
        } else {
            const float* A = (const float*)Av;
            #pragma unroll
            for (int r = 0; r < 8; ++r) {              // 128 rows x 16 float4
                const int id = tid + r * 256;
                const int m  = id >> 4;
                const int kq = (id & 15) << 2;
                const float4 v = *(const float4*)(A + (size_t)(m0 + m) * K + k0 + kq);
                bx4 s;
                if (ATYPE == 0) {
                    s[0] = f2bf(v.x); s[1] = f2bf(v.y); s[2] = f2bf(v.z); s[3] = f2bf(v.w);
                } else {
                    s[0] = f2h(v.x);  s[1] = f2h(v.y);  s[2] = f2h(v.z);  s[3] = f2h(v.w);
                }
                *(bx4*)&As[m * 72 + kq] = s;
            }
        }
        #pragma unroll
        for (int r = 0; r < 4; ++r) {                  // 128 rows x 8 short8
            const int id = tid + r * 256;
            const int n  = id >> 3;
            const int k8 = (id & 7) << 3;
            *(bx8*)&Bs[n * 72 + k8] = *(const bx8*)(Bt + (size_t)(n0 + n) * K + k0 + k8);
        }
        __syncthreads();

        #pragma unroll
        for (int ks = 0; ks < 2; ++ks) {
            bx8 af[4], bf[4];
            #pragma unroll
            for (int i = 0; i < 4; ++i)
                af[i] = *(const bx8*)&As[(wr + i * 16 + lr) * 72 + ks * 32 + ko];
            #pragma unroll
            for (int j = 0; j < 4; ++j)
                bf[j] = *(const bx8*)&Bs[(wc + j * 16 + lr) * 72 + ks * 32 + ko];
            #pragma unroll
            for (int i = 0; i < 4; ++i)
                #pragma unroll
                for (int j = 0; j < 4; ++j) {
                    if (F16)
                        acc[i][j] = __builtin_amdgcn_mfma_f32_16x16x32_f16(
                            __builtin_bit_cast(hx8, af[i]),
                            __builtin_bit_cast(hx8, bf[j]), acc[i][j], 0, 0, 0);
                    else
                        acc[i][j] = __builtin_amdgcn_mfma_f32_16x16x32_bf16(
                            af[i], bf[j], acc[i][j], 0, 0, 0);
                }
        }
        __syncthreads();
    }

    // Epilogue: C/D layout col=lane&15, row=(lane>>4)*4+reg
    const int rrow = (l >> 4) * 4;
    #pragma unroll
    for (int j = 0; j < 4; ++j) {
        const int col = n0 + wc + j * 16 + lr;
        if (NGUARD && col >= Nact) continue;
        const float bv = bias[col];
        #pragma unroll
        for (int i = 0; i < 4; ++i) {
            const int row = m0 + wr + i * 16 + rrow;
            #pragma unroll
            for (int r = 0; r < 4; ++r) {
                if (OUT_BF16)
                    ((short*)Cout)[(size_t)(row + r) * ldc + col] = f2bf(acc[i][j][r] + bv);
                else
                    ((float*)Cout)[(size_t)(row + r) * ldc + col] = acc[i][j][r] + bv;
            }
        }
    }
}

// ---------------------------------------------------------------------------
// Reference-point processing (verified round 1)
// ---------------------------------------------------------------------------
__global__ __launch_bounds__(256) void ref_kernel(
    const float* __restrict__ rp, float* __restrict__ refp)
{
    const int b = blockIdx.x;
    const float* r = rp + (size_t)b * LV * 2;
    const int tid = threadIdx.x;

    __shared__ float redx[256], redy[256];
    float sx = 0.f, sy = 0.f;
    for (int i = tid; i < 2304; i += 256) {
        sx += r[2 * i + 0];
        sy += r[2 * i + 1];
    }
    redx[tid] = sx; redy[tid] = sy;
    __syncthreads();
    for (int s = 128; s > 0; s >>= 1) {
        if (tid < s) { redx[tid] += redx[tid + s]; redy[tid] += redy[tid + s]; }
        __syncthreads();
    }
    const float p1x = redx[0] * (1.f / 2304.f);
    const float p1y = redy[0] * (1.f / 2304.f);

    const float* g = r + 2880 * 2;
    for (int q = tid; q < 576; q += 256) {
        const float p2x = r[(2304 + q) * 2 + 0];
        const float p2y = r[(2304 + q) * 2 + 1];
        const int qy = q / 24, qx = q % 24;
        const float syc = fminf(fmaxf(0.5f * qy - 0.25f, 0.f), 11.f);
        const float sxc = fminf(fmaxf(0.5f * qx - 0.25f, 0.f), 11.f);
        int y0 = min((int)syc, 10);
        int x0 = min((int)sxc, 10);
        const float fy = syc - (float)y0, fx = sxc - (float)x0;
        const float v00x = g[(y0 * 12 + x0) * 2 + 0],     v00y = g[(y0 * 12 + x0) * 2 + 1];
        const float v10x = g[(y0 * 12 + x0 + 1) * 2 + 0], v10y = g[(y0 * 12 + x0 + 1) * 2 + 1];
        const float v01x = g[((y0 + 1) * 12 + x0) * 2 + 0],     v01y = g[((y0 + 1) * 12 + x0) * 2 + 1];
        const float v11x = g[((y0 + 1) * 12 + x0 + 1) * 2 + 0], v11y = g[((y0 + 1) * 12 + x0 + 1) * 2 + 1];
        const float p3x = (1.f - fy) * ((1.f - fx) * v00x + fx * v10x)
                        + fy * ((1.f - fx) * v01x + fx * v11x);
        const float p3y = (1.f - fy) * ((1.f - fx) * v00y + fx * v10y)
                        + fy * ((1.f - fx) * v01y + fx * v11y);
        refp[((size_t)b * LQ + q) * 2 + 0] = (p1x + p2x + p3x) * (1.f / 3.f);
        refp[((size_t)b * LQ + q) * 2 + 1] = (p1y + p2y + p3y) * (1.f / 3.f);
    }
}

// ---------------------------------------------------------------------------
// Deformable sampling + softmax + attention accumulate.
// 192 threads: lane = (head h = tid>>5, channel pair c2 = (tid&31)*2).
// Gathers are ushort2 (4 B) -> half the loads of the scalar version; mid
// written as packed bf16x2 dwords.
// ---------------------------------------------------------------------------
__global__ __launch_bounds__(192) void sample_kernel(
    const unsigned short* __restrict__ val, const float* __restrict__ proj,
    const float* __restrict__ refp, unsigned* __restrict__ mid)
{
    const int i = blockIdx.x;
    const int g = i & 7;           // XCD group swizzle
    const int r = i >> 3;
    const int b = g * 4 + (r / LQ);
    const int q = r - (r / LQ) * LQ;
    const int bq = b * LQ + q;
    const int tid = threadIdx.x;

    __shared__ float attn[72];
    __shared__ int   sloc[72][4];
    __shared__ float swt[72][4];

    if (tid < 72) {
        attn[tid] = proj[(size_t)bq * NPROJ + 144 + tid];

        const int h = tid / 12;
        const int rr = tid % 12;
        const int l = rr >> 2;
        const int p = rr & 3;

        const int HL[3] = {48, 24, 12};
        const int ST[3] = {0, 2304, 2880};
        const int Hl = HL[l], Wl = HL[l], st = ST[l];

        const float rx = refp[bq * 2 + 0];
        const float ry = refp[bq * 2 + 1];
        const int oc = ((h * NLVL + l) * NPTS + p) * 2;
        const float cx = proj[(size_t)bq * NPROJ + oc + 0] + rx;
        const float cy = proj[(size_t)bq * NPROJ + oc + 1] + ry;

        const float px = cx * (float)Wl - 0.5f;
        const float py = cy * (float)Hl - 0.5f;
        const float x0f = floorf(px), y0f = floorf(py);
        const float lx = px - x0f, ly = py - y0f;
        const int x0 = (int)x0f, y0 = (int)y0f;

        #pragma unroll
        for (int k = 0; k < 4; ++k) {
            const int dx = k & 1, dy = k >> 1;
            const int xi = x0 + dx, yi = y0 + dy;
            const bool v = (xi >= 0) && (xi < Wl) && (yi >= 0) && (yi < Hl);
            const int xc = min(max(xi, 0), Wl - 1);
            const int yc = min(max(yi, 0), Hl - 1);
            sloc[tid][k] = st + yc * Wl + xc;
            const float wx = dx ? lx : 1.f - lx;
            const float wy = dy ? ly : 1.f - ly;
            swt[tid][k] = v ? wx * wy : 0.f;
        }
    }
    __syncthreads();

    if (tid < NHEAD) {
        float mx = -1e30f;
        #pragma unroll
        for (int j = 0; j < 12; ++j) mx = fmaxf(mx, attn[tid * 12 + j]);
        float s = 0.f;
        #pragma unroll
        for (int j = 0; j < 12; ++j) {
            const float e = expf(attn[tid * 12 + j] - mx);
            attn[tid * 12 + j] = e;
            s += e;
        }
        const float inv = 1.f / s;
        #pragma unroll
        for (int j = 0; j < 12; ++j) attn[tid * 12 + j] *= inv;
    }
    __syncthreads();

    const int h  = tid >> 5;            // head 0..5
    const int c2 = (tid & 31) << 1;     // channel pair 0,2,..,62
    const unsigned* vp = (const unsigned*)(val + (size_t)b * LV * CDIM + h * DHEAD + c2);
    float acc0 = 0.f, acc1 = 0.f;
    #pragma unroll
    for (int s = 0; s < 12; ++s) {
        const int j = h * 12 + s;
        const float a = attn[j];
        float s0 = 0.f, s1 = 0.f;
        #pragma unroll
        for (int k = 0; k < 4; ++k) {
            const unsigned u = vp[(size_t)sloc[j][k] * (CDIM / 2)];
            const float lo = __builtin_bit_cast(float, u << 16);
            const float hi = __builtin_bit_cast(float, u & 0xFFFF0000u);
            s0 += swt[j][k] * lo;
            s1 += swt[j][k] * hi;
        }
        acc0 += a * s0;
        acc1 += a * s1;
    }
    const unsigned lo = (unsigned)(unsigned short)f2bf(acc0);
    const unsigned hi = (unsigned)(unsigned short)f2bf(acc1);
    mid[((size_t)bq * CDIM + h * DHEAD + c2) >> 1] = lo | (hi << 16);
}

// ---------------------------------------------------------------------------
extern "C" void kernel_launch(void* const* d_in, const int* in_sizes, int n_in,
                              void* d_out, int out_size, void* d_ws, size_t ws_size,
                              hipStream_t stream)
{
    (void)in_sizes; (void)n_in; (void)out_size; (void)ws_size;

    const float* query   = (const float*)d_in[0];
    const float* value   = (const float*)d_in[1];
    const float* rp      = (const float*)d_in[2];
    const float* W_value = (const float*)d_in[3];
    const float* b_value = (const float*)d_in[4];
    const float* W_off   = (const float*)d_in[5];
    const float* b_off   = (const float*)d_in[6];
    const float* W_attn  = (const float*)d_in[7];
    const float* b_attn  = (const float*)d_in[8];
    const float* W_out   = (const float*)d_in[9];
    const float* b_out   = (const float*)d_in[10];
    float* out = (float*)d_out;

    // Workspace layout (256-B aligned chunks)
    char* p = (char*)d_ws;
    auto take = [&](size_t bytes) { char* q = p; p += (bytes + 255) & ~(size_t)255; return q; };
    short* val  = (short*)take((size_t)B_SZ * LV * CDIM * 2);     // bf16 val
    short* mid  = (short*)take((size_t)B_SZ * LQ * CDIM * 2);     // bf16 mid
    short* Wtv  = (short*)take((size_t)CDIM * CDIM * 2);          // bf16 W_value^T
    short* Wto  = (short*)take((size_t)CDIM * CDIM * 2);          // bf16 W_out^T
    short* Wf   = (short*)take((size_t)NPROJP * CDIM * 2);        // f16 [W_off|W_attn]^T padded
    float* proj = (float*)take((size_t)B_SZ * LQ * NPROJ * 4);
    float* refp = (float*)take((size_t)B_SZ * LQ * 2 * 4);
    float* bc   = (float*)take((size_t)NPROJP * 4);

    const int Mv = B_SZ * LV;   // 96768
    const int Mq = B_SZ * LQ;   // 18432

    // 0) weight prep (tiny)
    cast_transpose_kernel<<<(CDIM * CDIM + 255) / 256, 256, 0, stream>>>(
        W_value, Wtv, CDIM, CDIM);
    cast_transpose_kernel<<<(CDIM * CDIM + 255) / 256, 256, 0, stream>>>(
        W_out, Wto, CDIM, CDIM);
    prep_proj_f16_kernel<<<(NPROJP * CDIM + 255) / 256, 256, 0, stream>>>(
        W_off, b_off, W_attn, b_attn, Wf, bc);

    // 1) val = bf16(value @ W_value + b_value)
    gemm128_kernel<0, false, true, false><<<dim3(3, Mv / 128), 256, 0, stream>>>(
        value, Wtv, b_value, val, Mv, CDIM, CDIM, CDIM);
    // 2) proj = query @ [W_off|W_attn] + bias   (single f16 MFMA pass)
    gemm128_kernel<2, true, false, true><<<dim3(2, Mq / 128), 256, 0, stream>>>(
        query, Wf, bc, proj, Mq, CDIM, NPROJ, NPROJ);
    // 3) reference points
    ref_kernel<<<B_SZ, 256, 0, stream>>>(rp, refp);
    // 4) softmax + deformable sampling (XCD-swizzled, ushort2 gathers)
    sample_kernel<<<Mq, 192, 0, stream>>>(
        (const unsigned short*)val, proj, refp, (unsigned*)mid);
    // 5) out = mid @ W_out + b_out
    gemm128_kernel<1, false, false, false><<<dim3(3, Mq / 128), 256, 0, stream>>>(
        mid, Wto, b_out, out, Mq, CDIM, CDIM, CDIM);
}

// Round 7
// 399.107 us; speedup vs baseline: 1.1430x; 1.0693x over previous
//
#include <hip/hip_runtime.h>
#include <cmath>

// Problem constants
#define B_SZ   32
#define LQ     576
#define LV     3024
#define CDIM   384
#define NHEAD  6
#define DHEAD  64
#define NLVL   3
#define NPTS   4
#define NPROJ  216   // 144 offset channels + 72 attn logits
#define NPROJP 256   // padded to 2 x 128 col tiles

typedef short    bx4 __attribute__((ext_vector_type(4)));
typedef short    bx8 __attribute__((ext_vector_type(8)));
typedef float    fx4 __attribute__((ext_vector_type(4)));
typedef _Float16 hx8 __attribute__((ext_vector_type(8)));

__device__ __forceinline__ short f2bf(float f) {
    unsigned u = __builtin_bit_cast(unsigned, f);
    unsigned r = (u + 0x7FFFu + ((u >> 16) & 1u)) >> 16;  // RNE
    return (short)r;
}
__device__ __forceinline__ float bf2f(unsigned short u) {
    return __builtin_bit_cast(float, ((unsigned)u) << 16);
}
__device__ __forceinline__ short f2h(float f) {
    return __builtin_bit_cast(short, (_Float16)f);       // RNE
}

// ---------------------------------------------------------------------------
// fp32 -> bf16 elementwise cast, 8 elems/thread (pure bandwidth).
// ---------------------------------------------------------------------------
__global__ __launch_bounds__(256) void cast_bf16_kernel(
    const float4* __restrict__ in, bx8* __restrict__ outv, int n8)
{
    const int i = blockIdx.x * 256 + threadIdx.x;
    if (i >= n8) return;
    const float4 a = in[2 * i], b = in[2 * i + 1];
    bx8 s;
    s[0] = f2bf(a.x); s[1] = f2bf(a.y); s[2] = f2bf(a.z); s[3] = f2bf(a.w);
    s[4] = f2bf(b.x); s[5] = f2bf(b.y); s[6] = f2bf(b.z); s[7] = f2bf(b.w);
    outv[i] = s;
}

// ---------------------------------------------------------------------------
// W (K x N fp32) -> Wt (N x K bf16)   [384x384]
// ---------------------------------------------------------------------------
__global__ __launch_bounds__(256) void cast_transpose_kernel(
    const float* __restrict__ W, short* __restrict__ Wt, int K, int N)
{
    int idx = blockIdx.x * 256 + threadIdx.x;
    if (idx >= K * N) return;
    int n = idx / K, k = idx - n * K;
    Wt[idx] = f2bf(W[(size_t)k * N + n]);
}

// ---------------------------------------------------------------------------
// Concat f16 transposed weight for off+attn projection, padded to NPROJP.
// ---------------------------------------------------------------------------
__global__ __launch_bounds__(256) void prep_proj_f16_kernel(
    const float* __restrict__ W_off, const float* __restrict__ b_off,
    const float* __restrict__ W_attn, const float* __restrict__ b_attn,
    short* __restrict__ Wf, float* __restrict__ bc)
{
    int idx = blockIdx.x * 256 + threadIdx.x;
    if (idx >= NPROJP * CDIM) return;
    int n = idx / CDIM, k = idx - n * CDIM;
    float w = 0.f;
    if (n < 144)           w = W_off[(size_t)k * 144 + n];
    else if (n < NPROJ)    w = W_attn[(size_t)k * 72 + (n - 144)];
    Wf[idx] = f2h(w);
    if (idx < NPROJP)
        bc[idx] = (idx < 144) ? b_off[idx]
                 : (idx < NPROJ ? b_attn[idx - 144] : 0.f);
}

// ---------------------------------------------------------------------------
// m97-style DMA GEMM: C[M,384] = A[M,K](bf16) @ Bt[384,K](bf16)^T + bias.
// 128x128 tile, BK=64, 256 threads / 4 waves, acc[4][4].
// Staging uses __builtin_amdgcn_global_load_lds width=16 (direct HBM->LDS,
// no VGPR roundtrip / no VALU — rounds 3-6 all bottlenecked on the
// load->cast->ds_write staging path at MfmaUtil 8-11%).
// LDS layout: row-major [128][64] shorts with the k-octet (8 shorts = 16 B)
// XOR-swizzled by (row & 7). The swizzle is applied on the GLOBAL address
// (per-lane vector address); the LDS side is the hardware-fixed
// base + lane*16. Fragment ds_read_b128s then hit each bank-group exactly
// 8x64 lanes -> conflict-free. LDS = 2 x 16 KB.
// ---------------------------------------------------------------------------
template <bool OUT_BF16>
__global__ __launch_bounds__(256) void gemm_dma_kernel(
    const short* __restrict__ A, const short* __restrict__ Bt,
    const float* __restrict__ bias, void* __restrict__ Cout,
    int M, int K)
{
    constexpr int N = 384;
    __shared__ short As[128 * 64];
    __shared__ short Bs[128 * 64];

    const int tid = threadIdx.x;
    const int n0 = blockIdx.x * 128;
    const int m0 = blockIdx.y * 128;

    const int w  = tid >> 6;           // wave 0..3
    const int l  = tid & 63;
    const int wr = (w & 1) * 64;       // wave row offset
    const int wc = (w >> 1) * 64;      // wave col offset
    const int lr = l & 15;
    const int q  = l >> 4;             // lane quad 0..3

    // staging lane roles: 8 lanes x 16 B cover one row's 64-short K-slice
    const int rg  = l >> 3;            // row in 8-row group
    const int cg  = l & 7;             // physical octet this lane fills
    const int csw = cg ^ rg;           // global octet to fetch (XOR swizzle)

    fx4 acc[4][4] = {};

    for (int k0 = 0; k0 < K; k0 += 64) {
        // ---- DMA staging: 4 insts/wave for A, 4 for B (1 KB each) ----
        #pragma unroll
        for (int t = 0; t < 4; ++t) {
            const int rbase = w * 32 + t * 8;          // wave-uniform
            const short* gA = A + (size_t)(m0 + rbase + rg) * K + k0 + csw * 8;
            __builtin_amdgcn_global_load_lds(
                (const __attribute__((address_space(1))) void*)gA,
                (__attribute__((address_space(3))) void*)&As[rbase * 64],
                16, 0, 0);
            const short* gB = Bt + (size_t)(n0 + rbase + rg) * K + k0 + csw * 8;
            __builtin_amdgcn_global_load_lds(
                (const __attribute__((address_space(1))) void*)gB,
                (__attribute__((address_space(3))) void*)&Bs[rbase * 64],
                16, 0, 0);
        }
        __syncthreads();

        // ---- MFMA: 2 k-steps of 32; octet c = ks*4 + q, de-swizzle by lr&7
        #pragma unroll
        for (int ks = 0; ks < 2; ++ks) {
            bx8 af[4], bf[4];
            #pragma unroll
            for (int i = 0; i < 4; ++i)
                af[i] = *(const bx8*)&As[(wr + i * 16 + lr) * 64 +
                                         (((ks * 4 + q) ^ (lr & 7)) << 3)];
            #pragma unroll
            for (int j = 0; j < 4; ++j)
                bf[j] = *(const bx8*)&Bs[(wc + j * 16 + lr) * 64 +
                                         (((ks * 4 + q) ^ (lr & 7)) << 3)];
            #pragma unroll
            for (int i = 0; i < 4; ++i)
                #pragma unroll
                for (int j = 0; j < 4; ++j)
                    acc[i][j] = __builtin_amdgcn_mfma_f32_16x16x32_bf16(
                        af[i], bf[j], acc[i][j], 0, 0, 0);
        }
        __syncthreads();
    }

    // Epilogue: C/D layout col=lane&15, row=(lane>>4)*4+reg
    const int rrow = q * 4;
    #pragma unroll
    for (int j = 0; j < 4; ++j) {
        const int col = n0 + wc + j * 16 + lr;
        const float bv = bias[col];
        #pragma unroll
        for (int i = 0; i < 4; ++i) {
            const int row = m0 + wr + i * 16 + rrow;
            #pragma unroll
            for (int r = 0; r < 4; ++r) {
                if (OUT_BF16)
                    ((short*)Cout)[(size_t)(row + r) * N + col] = f2bf(acc[i][j][r] + bv);
                else
                    ((float*)Cout)[(size_t)(row + r) * N + col] = acc[i][j][r] + bv;
            }
        }
    }
}

// ---------------------------------------------------------------------------
// f16 MFMA GEMM for the query projection (fp32 A cast in-flight).
// 128x128 tile, BK=64, 256 threads. No launch-bound cap (round-6 lesson:
// capping VGPRs starves load batching).
// ---------------------------------------------------------------------------
__global__ __launch_bounds__(256) void gemm_proj_kernel(
    const float* __restrict__ A, const short* __restrict__ Wf,
    const float* __restrict__ bias, float* __restrict__ C,
    int M, int K)
{
    __shared__ short As[128 * 72];
    __shared__ short Bs[128 * 72];

    const int tid = threadIdx.x;
    const int n0 = blockIdx.x * 128;
    const int m0 = blockIdx.y * 128;

    const int w  = tid >> 6;
    const int l  = tid & 63;
    const int wr = (w & 1) * 64;
    const int wc = (w >> 1) * 64;
    const int lr = l & 15;
    const int ko = (l >> 4) * 8;

    fx4 acc[4][4] = {};

    for (int k0 = 0; k0 < K; k0 += 64) {
        #pragma unroll
        for (int r = 0; r < 8; ++r) {
            const int id = tid + r * 256;
            const int m  = id >> 4;
            const int kq = (id & 15) << 2;
            const float4 v = *(const float4*)(A + (size_t)(m0 + m) * K + k0 + kq);
            bx4 s;
            s[0] = f2h(v.x); s[1] = f2h(v.y); s[2] = f2h(v.z); s[3] = f2h(v.w);
            *(bx4*)&As[m * 72 + kq] = s;
        }
        #pragma unroll
        for (int r = 0; r < 4; ++r) {
            const int id = tid + r * 256;
            const int n  = id >> 3;
            const int k8 = (id & 7) << 3;
            *(bx8*)&Bs[n * 72 + k8] = *(const bx8*)(Wf + (size_t)(n0 + n) * K + k0 + k8);
        }
        __syncthreads();

        #pragma unroll
        for (int ks = 0; ks < 2; ++ks) {
            bx8 af[4], bf[4];
            #pragma unroll
            for (int i = 0; i < 4; ++i)
                af[i] = *(const bx8*)&As[(wr + i * 16 + lr) * 72 + ks * 32 + ko];
            #pragma unroll
            for (int j = 0; j < 4; ++j)
                bf[j] = *(const bx8*)&Bs[(wc + j * 16 + lr) * 72 + ks * 32 + ko];
            #pragma unroll
            for (int i = 0; i < 4; ++i)
                #pragma unroll
                for (int j = 0; j < 4; ++j)
                    acc[i][j] = __builtin_amdgcn_mfma_f32_16x16x32_f16(
                        __builtin_bit_cast(hx8, af[i]),
                        __builtin_bit_cast(hx8, bf[j]), acc[i][j], 0, 0, 0);
        }
        __syncthreads();
    }

    const int rrow = (l >> 4) * 4;
    #pragma unroll
    for (int j = 0; j < 4; ++j) {
        const int col = n0 + wc + j * 16 + lr;
        if (col >= NPROJ) continue;
        const float bv = bias[col];
        #pragma unroll
        for (int i = 0; i < 4; ++i) {
            const int row = m0 + wr + i * 16 + rrow;
            #pragma unroll
            for (int r = 0; r < 4; ++r)
                C[(size_t)(row + r) * NPROJ + col] = acc[i][j][r] + bv;
        }
    }
}

// ---------------------------------------------------------------------------
// Reference-point processing (verified round 1)
// ---------------------------------------------------------------------------
__global__ __launch_bounds__(256) void ref_kernel(
    const float* __restrict__ rp, float* __restrict__ refp)
{
    const int b = blockIdx.x;
    const float* r = rp + (size_t)b * LV * 2;
    const int tid = threadIdx.x;

    __shared__ float redx[256], redy[256];
    float sx = 0.f, sy = 0.f;
    for (int i = tid; i < 2304; i += 256) {
        sx += r[2 * i + 0];
        sy += r[2 * i + 1];
    }
    redx[tid] = sx; redy[tid] = sy;
    __syncthreads();
    for (int s = 128; s > 0; s >>= 1) {
        if (tid < s) { redx[tid] += redx[tid + s]; redy[tid] += redy[tid + s]; }
        __syncthreads();
    }
    const float p1x = redx[0] * (1.f / 2304.f);
    const float p1y = redy[0] * (1.f / 2304.f);

    const float* g = r + 2880 * 2;
    for (int q = tid; q < 576; q += 256) {
        const float p2x = r[(2304 + q) * 2 + 0];
        const float p2y = r[(2304 + q) * 2 + 1];
        const int qy = q / 24, qx = q % 24;
        const float syc = fminf(fmaxf(0.5f * qy - 0.25f, 0.f), 11.f);
        const float sxc = fminf(fmaxf(0.5f * qx - 0.25f, 0.f), 11.f);
        int y0 = min((int)syc, 10);
        int x0 = min((int)sxc, 10);
        const float fy = syc - (float)y0, fx = sxc - (float)x0;
        const float v00x = g[(y0 * 12 + x0) * 2 + 0],     v00y = g[(y0 * 12 + x0) * 2 + 1];
        const float v10x = g[(y0 * 12 + x0 + 1) * 2 + 0], v10y = g[(y0 * 12 + x0 + 1) * 2 + 1];
        const float v01x = g[((y0 + 1) * 12 + x0) * 2 + 0],     v01y = g[((y0 + 1) * 12 + x0) * 2 + 1];
        const float v11x = g[((y0 + 1) * 12 + x0 + 1) * 2 + 0], v11y = g[((y0 + 1) * 12 + x0 + 1) * 2 + 1];
        const float p3x = (1.f - fy) * ((1.f - fx) * v00x + fx * v10x)
                        + fy * ((1.f - fx) * v01x + fx * v11x);
        const float p3y = (1.f - fy) * ((1.f - fx) * v00y + fx * v10y)
                        + fy * ((1.f - fx) * v01y + fx * v11y);
        refp[((size_t)b * LQ + q) * 2 + 0] = (p1x + p2x + p3x) * (1.f / 3.f);
        refp[((size_t)b * LQ + q) * 2 + 1] = (p1y + p2y + p3y) * (1.f / 3.f);
    }
}

// ---------------------------------------------------------------------------
// Deformable sampling + softmax + attention accumulate (verified round 6).
// 192 threads, ushort2 gathers, XCD-swizzled block order.
// ---------------------------------------------------------------------------
__global__ __launch_bounds__(192) void sample_kernel(
    const unsigned short* __restrict__ val, const float* __restrict__ proj,
    const float* __restrict__ refp, unsigned* __restrict__ mid)
{
    const int i = blockIdx.x;
    const int g = i & 7;
    const int r = i >> 3;
    const int b = g * 4 + (r / LQ);
    const int q = r - (r / LQ) * LQ;
    const int bq = b * LQ + q;
    const int tid = threadIdx.x;

    __shared__ float attn[72];
    __shared__ int   sloc[72][4];
    __shared__ float swt[72][4];

    if (tid < 72) {
        attn[tid] = proj[(size_t)bq * NPROJ + 144 + tid];

        const int h = tid / 12;
        const int rr = tid % 12;
        const int l = rr >> 2;
        const int p = rr & 3;

        const int HL[3] = {48, 24, 12};
        const int ST[3] = {0, 2304, 2880};
        const int Hl = HL[l], Wl = HL[l], st = ST[l];

        const float rx = refp[bq * 2 + 0];
        const float ry = refp[bq * 2 + 1];
        const int oc = ((h * NLVL + l) * NPTS + p) * 2;
        const float cx = proj[(size_t)bq * NPROJ + oc + 0] + rx;
        const float cy = proj[(size_t)bq * NPROJ + oc + 1] + ry;

        const float px = cx * (float)Wl - 0.5f;
        const float py = cy * (float)Hl - 0.5f;
        const float x0f = floorf(px), y0f = floorf(py);
        const float lx = px - x0f, ly = py - y0f;
        const int x0 = (int)x0f, y0 = (int)y0f;

        #pragma unroll
        for (int k = 0; k < 4; ++k) {
            const int dx = k & 1, dy = k >> 1;
            const int xi = x0 + dx, yi = y0 + dy;
            const bool v = (xi >= 0) && (xi < Wl) && (yi >= 0) && (yi < Hl);
            const int xc = min(max(xi, 0), Wl - 1);
            const int yc = min(max(yi, 0), Hl - 1);
            sloc[tid][k] = st + yc * Wl + xc;
            const float wx = dx ? lx : 1.f - lx;
            const float wy = dy ? ly : 1.f - ly;
            swt[tid][k] = v ? wx * wy : 0.f;
        }
    }
    __syncthreads();

    if (tid < NHEAD) {
        float mx = -1e30f;
        #pragma unroll
        for (int j = 0; j < 12; ++j) mx = fmaxf(mx, attn[tid * 12 + j]);
        float s = 0.f;
        #pragma unroll
        for (int j = 0; j < 12; ++j) {
            const float e = expf(attn[tid * 12 + j] - mx);
            attn[tid * 12 + j] = e;
            s += e;
        }
        const float inv = 1.f / s;
        #pragma unroll
        for (int j = 0; j < 12; ++j) attn[tid * 12 + j] *= inv;
    }
    __syncthreads();

    const int h  = tid >> 5;
    const int c2 = (tid & 31) << 1;
    const unsigned* vp = (const unsigned*)(val + (size_t)b * LV * CDIM + h * DHEAD + c2);
    float acc0 = 0.f, acc1 = 0.f;
    #pragma unroll
    for (int s = 0; s < 12; ++s) {
        const int j = h * 12 + s;
        const float a = attn[j];
        float s0 = 0.f, s1 = 0.f;
        #pragma unroll
        for (int k = 0; k < 4; ++k) {
            const unsigned u = vp[(size_t)sloc[j][k] * (CDIM / 2)];
            const float lo = __builtin_bit_cast(float, u << 16);
            const float hi = __builtin_bit_cast(float, u & 0xFFFF0000u);
            s0 += swt[j][k] * lo;
            s1 += swt[j][k] * hi;
        }
        acc0 += a * s0;
        acc1 += a * s1;
    }
    const unsigned lo = (unsigned)(unsigned short)f2bf(acc0);
    const unsigned hi = (unsigned)(unsigned short)f2bf(acc1);
    mid[((size_t)bq * CDIM + h * DHEAD + c2) >> 1] = lo | (hi << 16);
}

// ---------------------------------------------------------------------------
extern "C" void kernel_launch(void* const* d_in, const int* in_sizes, int n_in,
                              void* d_out, int out_size, void* d_ws, size_t ws_size,
                              hipStream_t stream)
{
    (void)in_sizes; (void)n_in; (void)out_size; (void)ws_size;

    const float* query   = (const float*)d_in[0];
    const float* value   = (const float*)d_in[1];
    const float* rp      = (const float*)d_in[2];
    const float* W_value = (const float*)d_in[3];
    const float* b_value = (const float*)d_in[4];
    const float* W_off   = (const float*)d_in[5];
    const float* b_off   = (const float*)d_in[6];
    const float* W_attn  = (const float*)d_in[7];
    const float* b_attn  = (const float*)d_in[8];
    const float* W_out   = (const float*)d_in[9];
    const float* b_out   = (const float*)d_in[10];
    float* out = (float*)d_out;

    // Workspace layout (256-B aligned chunks)
    char* p = (char*)d_ws;
    auto take = [&](size_t bytes) { char* q = p; p += (bytes + 255) & ~(size_t)255; return q; };
    short* valb = (short*)take((size_t)B_SZ * LV * CDIM * 2);     // bf16 value
    short* val  = (short*)take((size_t)B_SZ * LV * CDIM * 2);     // bf16 val
    short* mid  = (short*)take((size_t)B_SZ * LQ * CDIM * 2);     // bf16 mid
    short* Wtv  = (short*)take((size_t)CDIM * CDIM * 2);          // bf16 W_value^T
    short* Wto  = (short*)take((size_t)CDIM * CDIM * 2);          // bf16 W_out^T
    short* Wf   = (short*)take((size_t)NPROJP * CDIM * 2);        // f16 proj W^T
    float* proj = (float*)take((size_t)B_SZ * LQ * NPROJ * 4);
    float* refp = (float*)take((size_t)B_SZ * LQ * 2 * 4);
    float* bc   = (float*)take((size_t)NPROJP * 4);

    const int Mv = B_SZ * LV;   // 96768
    const int Mq = B_SZ * LQ;   // 18432
    const int nv8 = Mv * CDIM / 8;

    // 0) weight prep (tiny) + value cast (bandwidth)
    cast_transpose_kernel<<<(CDIM * CDIM + 255) / 256, 256, 0, stream>>>(
        W_value, Wtv, CDIM, CDIM);
    cast_transpose_kernel<<<(CDIM * CDIM + 255) / 256, 256, 0, stream>>>(
        W_out, Wto, CDIM, CDIM);
    prep_proj_f16_kernel<<<(NPROJP * CDIM + 255) / 256, 256, 0, stream>>>(
        W_off, b_off, W_attn, b_attn, Wf, bc);
    cast_bf16_kernel<<<(nv8 + 255) / 256, 256, 0, stream>>>(
        (const float4*)value, (bx8*)valb, nv8);

    // 1) val = bf16(valb @ W_value + b_value)   (DMA-staged MFMA)
    gemm_dma_kernel<true><<<dim3(3, Mv / 128), 256, 0, stream>>>(
        valb, Wtv, b_value, val, Mv, CDIM);
    // 2) proj = query @ [W_off|W_attn] + bias   (f16 MFMA)
    gemm_proj_kernel<<<dim3(2, Mq / 128), 256, 0, stream>>>(
        query, Wf, bc, proj, Mq, CDIM);
    // 3) reference points
    ref_kernel<<<B_SZ, 256, 0, stream>>>(rp, refp);
    // 4) softmax + deformable sampling (XCD-swizzled)
    sample_kernel<<<Mq, 192, 0, stream>>>(
        (const unsigned short*)val, proj, refp, (unsigned*)mid);
    // 5) out = mid @ W_out + b_out              (DMA-staged MFMA)
    gemm_dma_kernel<false><<<dim3(3, Mq / 128), 256, 0, stream>>>(
        mid, Wto, b_out, out, Mq, CDIM);
}